// Round 3
// baseline (127.616 us; speedup 1.0000x reference)
//
#include <hip/hip_runtime.h>

typedef unsigned short ushort;
typedef __attribute__((ext_vector_type(8))) short short8;
typedef __attribute__((ext_vector_type(4))) float floatx4;

// Problem constants
#define T_STEPS 100
#define BATCH   32
#define NIN     1024
#define NOUT    512

// K layout: k = b*SEG + t, segment padded 100 -> 112 (16B-aligned, BK-multiple)
#define SEG     112
#define KPAD    (BATCH * SEG)          // 3584
#define KPADB   (KPAD * 2)             // row bytes
#define KS      8
#define KCHUNK  (KPAD / KS)            // 448
#define BK      32

#define LR_LTP  (1e-4f)
#define LR_LTD  (-1e-4f)
#define INV_B   (1.0f / 32.0f)
#define DECAY   0.951229424500714f     // float(exp(-1/20))

// Output layout (floats): [delta_w | pre_tr_final | post_tr_final]
#define OFF_PRE  (NOUT * NIN)
#define OFF_POST (OFF_PRE + BATCH * NIN)

// Workspace layout (ushort elements): four transposed bf16 operands, [rows][KPAD]
#define U_PRST  0                            // pre_s_t   [NIN ][KPAD]
#define U_PRTT  (U_PRST + NIN * KPAD)        // pre_tr_t  [NIN ][KPAD]
#define U_POST  (U_PRTT + NIN * KPAD)        // post_s_t  [NOUT][KPAD]
#define U_POTT  (U_POST + NOUT * KPAD)       // post_tr_t [NOUT][KPAD]

static __device__ __forceinline__ ushort f2bf(float f) {
    union { float f; unsigned int u; } v; v.f = f;
    unsigned int r = (v.u + 0x7FFFu + ((v.u >> 16) & 1u)) >> 16;   // RNE
    return (ushort)r;
}

// ---------------------------------------------------------------------------
// Kernel 1: trace recurrence fused with transpose.
// One thread per (b, channel). Accumulates 100 bf16 trace + 100 bf16 spike
// values in registers (packed 2/dword), then writes both rows contiguously
// at [ch][b*SEG .. b*SEG+112) as 14 x uint4 (zero-padded tail).
// Also zero-inits the dw region of out and writes final fp32 traces.
// ---------------------------------------------------------------------------
__global__ __launch_bounds__(256, 1) void stdp_traces_t(
    const float* __restrict__ pre_s,    // [T,B,NIN]
    const float* __restrict__ post_s,   // [T,B,NOUT]
    const float* __restrict__ pre_tr0,  // [B,NIN]
    const float* __restrict__ post_tr0, // [B,NOUT]
    ushort* __restrict__ pre_s_t, ushort* __restrict__ pre_tr_t,
    ushort* __restrict__ post_s_t, ushort* __restrict__ post_tr_t,
    float* __restrict__ out)
{
    const int tid = blockIdx.x * blockDim.x + threadIdx.x;

    // zero-init dw region for the GEMM's atomics
    {
        const float4 z4 = make_float4(0.f, 0.f, 0.f, 0.f);
        #pragma unroll
        for (int k = 0; k < 3; ++k) {
            const int j = tid + k * (BATCH * (NIN + NOUT));
            if (j < (NOUT * NIN) / 4) ((float4*)out)[j] = z4;
        }
    }

    unsigned int trp[56];
    unsigned int spp[56];
    #pragma unroll
    for (int j = 50; j < 56; ++j) { trp[j] = 0u; spp[j] = 0u; }

    const float* src; const float* init;
    ushort *dst_s, *dst_t;
    int nch, id, outoff;
    if (tid < BATCH * NIN) {
        src = pre_s;  init = pre_tr0;  dst_s = pre_s_t;  dst_t = pre_tr_t;
        nch = NIN;  id = tid;               outoff = OFF_PRE;
    } else {
        src = post_s; init = post_tr0; dst_s = post_s_t; dst_t = post_tr_t;
        nch = NOUT; id = tid - BATCH * NIN; outoff = OFF_POST;
    }

    const size_t stride = (size_t)BATCH * nch;
    float tr = init[id];
    #pragma unroll
    for (int t0 = 0; t0 < T_STEPS; t0 += 10) {
        float s[10];
        #pragma unroll
        for (int j = 0; j < 10; ++j)
            s[j] = src[(size_t)(t0 + j) * stride + id];
        #pragma unroll
        for (int j = 0; j < 10; ++j) {
            const int t = t0 + j;
            tr = tr * DECAY + s[j];
            const unsigned int tb = (unsigned int)f2bf(tr);
            const unsigned int sb = (unsigned int)f2bf(s[j]);
            if (t & 1) { trp[t >> 1] |= tb << 16; spp[t >> 1] |= sb << 16; }
            else       { trp[t >> 1]  = tb;       spp[t >> 1]  = sb;       }
        }
    }
    out[outoff + id] = tr;

    const int b  = id / nch;     // nch is a power of two
    const int ch = id - b * nch;
    ushort* rs = dst_s + (size_t)ch * KPAD + b * SEG;   // 16B-aligned
    ushort* rt = dst_t + (size_t)ch * KPAD + b * SEG;
    #pragma unroll
    for (int c = 0; c < 14; ++c) {
        const uint4 vs = make_uint4(spp[4*c], spp[4*c+1], spp[4*c+2], spp[4*c+3]);
        const uint4 vt = make_uint4(trp[4*c], trp[4*c+1], trp[4*c+2], trp[4*c+3]);
        ((uint4*)rs)[c] = vs;
        ((uint4*)rt)[c] = vt;
    }
}

// ---------------------------------------------------------------------------
// Kernel 2: dual bf16 MFMA GEMM with fused finalize.
//   P[o,i] = sum_k post_s[k,o]*pre_tr[k,i]
//   D[o,i] = sum_k post_tr[k,o]*pre_s[k,i]
//   dw[o,i] += (LR_LTP*(1-w)*P + LR_LTD*w*D)/B     (atomicAdd per K-chunk)
// 128x128 tile, BK=32, 4 waves 2x2, 16x16x32 MFMA, global_load_lds w=16.
// grid = (NIN/128, NOUT/128, KS)
// ---------------------------------------------------------------------------
__global__ __launch_bounds__(256) void stdp_gemm_dual(
    const ushort* __restrict__ post_s_t, const ushort* __restrict__ pre_tr_t,
    const ushort* __restrict__ post_tr_t, const ushort* __restrict__ pre_s_t,
    const float* __restrict__ wmat, float* __restrict__ out)
{
    __shared__ ushort AsP[128 * 32];   // post_s  rows (M)
    __shared__ ushort AsD[128 * 32];   // post_tr rows (M)
    __shared__ ushort BsP[128 * 32];   // pre_tr  rows (N)
    __shared__ ushort BsD[128 * 32];   // pre_s   rows (N)

    const int i0 = blockIdx.x * 128;
    const int o0 = blockIdx.y * 128;
    const int k0 = blockIdx.z * KCHUNK;

    const int tid  = threadIdx.x;
    const int w    = tid >> 6;
    const int lane = tid & 63;
    const int quad = lane >> 4;
    const int l16  = lane & 15;
    const int wm   = w & 1;
    const int wn   = w >> 1;

    floatx4 accP[4][4];
    floatx4 accD[4][4];
    const floatx4 zero4 = {0.f, 0.f, 0.f, 0.f};
    #pragma unroll
    for (int mt = 0; mt < 4; ++mt)
        #pragma unroll
        for (int nt = 0; nt < 4; ++nt) { accP[mt][nt] = zero4; accD[mt][nt] = zero4; }

    for (int kb = k0; kb < k0 + KCHUNK; kb += BK) {
        #pragma unroll
        for (int q = 0; q < 2; ++q) {
            const int c   = w * 128 + q * 64 + lane;   // 16B chunk id 0..511
            const int row = c >> 2;
            const int kob = (c & 3) * 16;
            const size_t aoff = (size_t)(o0 + row) * KPADB + kb * 2 + kob;
            const size_t boff = (size_t)(i0 + row) * KPADB + kb * 2 + kob;
            const int ldso = w * 2048 + q * 1024;
            __builtin_amdgcn_global_load_lds(
                (const __attribute__((address_space(1))) void*)((const char*)post_s_t + aoff),
                (__attribute__((address_space(3))) void*)((char*)AsP + ldso), 16, 0, 0);
            __builtin_amdgcn_global_load_lds(
                (const __attribute__((address_space(1))) void*)((const char*)post_tr_t + aoff),
                (__attribute__((address_space(3))) void*)((char*)AsD + ldso), 16, 0, 0);
            __builtin_amdgcn_global_load_lds(
                (const __attribute__((address_space(1))) void*)((const char*)pre_tr_t + boff),
                (__attribute__((address_space(3))) void*)((char*)BsP + ldso), 16, 0, 0);
            __builtin_amdgcn_global_load_lds(
                (const __attribute__((address_space(1))) void*)((const char*)pre_s_t + boff),
                (__attribute__((address_space(3))) void*)((char*)BsD + ldso), 16, 0, 0);
        }
        __syncthreads();

        short8 aP[4], aD[4], bP[4], bD[4];
        #pragma unroll
        for (int mt = 0; mt < 4; ++mt) {
            const int r = (wm * 64 + mt * 16 + l16) * 32 + quad * 8;
            aP[mt] = *(const short8*)&AsP[r];
            aD[mt] = *(const short8*)&AsD[r];
        }
        #pragma unroll
        for (int nt = 0; nt < 4; ++nt) {
            const int r = (wn * 64 + nt * 16 + l16) * 32 + quad * 8;
            bP[nt] = *(const short8*)&BsP[r];
            bD[nt] = *(const short8*)&BsD[r];
        }
        #pragma unroll
        for (int mt = 0; mt < 4; ++mt)
            #pragma unroll
            for (int nt = 0; nt < 4; ++nt) {
                accP[mt][nt] = __builtin_amdgcn_mfma_f32_16x16x32_bf16(
                    aP[mt], bP[nt], accP[mt][nt], 0, 0, 0);
                accD[mt][nt] = __builtin_amdgcn_mfma_f32_16x16x32_bf16(
                    aD[mt], bD[nt], accD[mt][nt], 0, 0, 0);
            }
        __syncthreads();
    }

    // epilogue: C/D layout col = lane&15 (i), row = quad*4+reg (o)
    const float c1 = LR_LTP * INV_B;
    const float c2 = LR_LTD * INV_B;
    #pragma unroll
    for (int mt = 0; mt < 4; ++mt) {
        const int obase = o0 + wm * 64 + mt * 16 + quad * 4;
        #pragma unroll
        for (int nt = 0; nt < 4; ++nt) {
            const int i = i0 + wn * 64 + nt * 16 + l16;
            #pragma unroll
            for (int r = 0; r < 4; ++r) {
                const size_t idx = (size_t)(obase + r) * NIN + i;
                const float wv = wmat[idx];
                const float v = c1 * (1.0f - wv) * accP[mt][nt][r]
                              + c2 * wv          * accD[mt][nt][r];
                atomicAdd(&out[idx], v);
            }
        }
    }
}

extern "C" void kernel_launch(void* const* d_in, const int* in_sizes, int n_in,
                              void* d_out, int out_size, void* d_ws, size_t ws_size,
                              hipStream_t stream) {
    const float* weight   = (const float*)d_in[0];
    const float* pre_s    = (const float*)d_in[1];
    const float* post_s   = (const float*)d_in[2];
    const float* pre_tr0  = (const float*)d_in[3];
    const float* post_tr0 = (const float*)d_in[4];
    float* out = (float*)d_out;

    ushort* u = (ushort*)d_ws;
    ushort* pre_s_t   = u + U_PRST;
    ushort* pre_tr_t  = u + U_PRTT;
    ushort* post_s_t  = u + U_POST;
    ushort* post_tr_t = u + U_POTT;

    stdp_traces_t<<<dim3(BATCH * (NIN + NOUT) / 256), dim3(256), 0, stream>>>(
        pre_s, post_s, pre_tr0, post_tr0,
        pre_s_t, pre_tr_t, post_s_t, post_tr_t, out);

    stdp_gemm_dual<<<dim3(NIN / 128, NOUT / 128, KS), dim3(256), 0, stream>>>(
        post_s_t, pre_tr_t, post_tr_t, pre_s_t, weight, out);
}

// Round 4
// 111.798 us; speedup vs baseline: 1.1415x; 1.1415x over previous
//
#include <hip/hip_runtime.h>

typedef unsigned short ushort;
typedef __attribute__((ext_vector_type(8))) short short8;
typedef __attribute__((ext_vector_type(8))) ushort ushort8;
typedef __attribute__((ext_vector_type(4))) float floatx4;

// Problem constants
#define T_STEPS 100
#define BATCH   32
#define NIN     1024
#define NOUT    512
#define KTOT    (T_STEPS * BATCH)      // 3200, k = t*B + b (natural order)
#define KROWB   (KTOT * 2)             // transposed row bytes = 6400

#define KS      5
#define KCHUNK  (KTOT / KS)            // 640
#define BK      32

#define LR_LTP  (1e-4f)
#define LR_LTD  (-1e-4f)
#define INV_B   (1.0f / 32.0f)
#define DECAY   0.951229424500714f     // exp(-1/20)
#define D25     0.286504796860190f     // exp(-25/20)
#define TCH     25                     // t-chunk per thread
#define NCHUNK  4

// Output layout (floats): [delta_w | pre_tr_final | post_tr_final]
#define OFF_PRE  (NOUT * NIN)
#define OFF_POST (OFF_PRE + BATCH * NIN)

// Workspace layout (ushort elements):
//   ws_pre16  [KTOT][B*NIN ... i.e. [T][B][NIN]]  k-major bf16 traces
//   ws_post16 [T][B][NOUT]
//   pre_s_t   [NIN ][KTOT]  transposed bf16
//   post_s_t  [NOUT][KTOT]
//   pre_tr_t  [NIN ][KTOT]
//   post_tr_t [NOUT][KTOT]
#define U_WSPRE   0
#define U_WSPOST  (U_WSPRE + KTOT * NIN)
#define U_PRST    (U_WSPOST + KTOT * NOUT)
#define U_POST_ST (U_PRST + NIN * KTOT)
#define U_PRTT    (U_POST_ST + NOUT * KTOT)
#define U_POTT    (U_PRTT + NIN * KTOT)

static __device__ __forceinline__ ushort f2bf(float f) {
    union { float f; unsigned int u; } v; v.f = f;
    unsigned int r = (v.u + 0x7FFFu + ((v.u >> 16) & 1u)) >> 16;   // RNE
    return (ushort)r;
}

// ---------------------------------------------------------------------------
// Kernel 1: trace recurrence, T split 4-ways per chain with LDS carry scan.
// Block = 64 chains x 4 t-chunks. 768 blocks (3/CU). Also zero-inits the dw
// region of out and writes final fp32 traces.
// ---------------------------------------------------------------------------
__global__ __launch_bounds__(256) void stdp_traces(
    const float* __restrict__ pre_s,    // [T,B,NIN]
    const float* __restrict__ post_s,   // [T,B,NOUT]
    const float* __restrict__ pre_tr0,  // [B,NIN]
    const float* __restrict__ post_tr0, // [B,NOUT]
    ushort* __restrict__ ws_pre16,      // [T,B,NIN] bf16
    ushort* __restrict__ ws_post16,     // [T,B,NOUT]
    float* __restrict__ out)
{
    __shared__ float Eend[NCHUNK][64];

    // zero-init dw region for the GEMM's atomics (first 512 blocks cover it)
    {
        const int j = blockIdx.x * 256 + threadIdx.x;
        if (j < (NOUT * NIN) / 4)
            ((float4*)out)[j] = make_float4(0.f, 0.f, 0.f, 0.f);
    }

    const int chain = threadIdx.x & 63;   // lane
    const int c     = threadIdx.x >> 6;   // t-chunk (wave-uniform)
    int gchain = blockIdx.x * 64 + chain;

    const float* src; const float* init; ushort* dst;
    int id, stride, outoff;
    if (gchain < BATCH * NIN) {
        src = pre_s;  init = pre_tr0;  dst = ws_pre16;
        id = gchain;  stride = BATCH * NIN;  outoff = OFF_PRE;
    } else {
        src = post_s; init = post_tr0; dst = ws_post16;
        id = gchain - BATCH * NIN; stride = BATCH * NOUT; outoff = OFF_POST;
    }

    const int t0 = c * TCH;
    float x[TCH];
    #pragma unroll
    for (int m = 0; m < TCH; ++m)
        x[m] = src[(size_t)(t0 + m) * stride + id];

    float e = 0.f;
    #pragma unroll
    for (int m = 0; m < TCH; ++m) { e = e * DECAY + x[m]; x[m] = e; }
    Eend[c][chain] = e;
    __syncthreads();

    // carry into chunk c: C = ((init*d25 + E0)*d25 + E1)... (wave-uniform trip)
    float C = init[id];
    for (int cc = 0; cc < c; ++cc)
        C = C * D25 + Eend[cc][chain];

    float p = C * DECAY;
    #pragma unroll
    for (int m = 0; m < TCH; ++m) { x[m] += p; p *= DECAY; }

    #pragma unroll
    for (int m = 0; m < TCH; ++m)
        dst[(size_t)(t0 + m) * stride + id] = f2bf(x[m]);

    if (c == NCHUNK - 1)
        out[outoff + id] = x[TCH - 1];
}

// ---------------------------------------------------------------------------
// Kernel 2: transpose all four operands to [N][K] bf16 row-major.
// 64x64 tiles via LDS. grid = (KTOT/64=50, 48); y selects region.
// ---------------------------------------------------------------------------
__global__ __launch_bounds__(256) void stdp_transpose(
    const float* __restrict__ pre_s, const float* __restrict__ post_s,
    const ushort* __restrict__ ws_pre16, const ushort* __restrict__ ws_post16,
    ushort* __restrict__ pre_s_t, ushort* __restrict__ post_s_t,
    ushort* __restrict__ pre_tr_t, ushort* __restrict__ post_tr_t)
{
    __shared__ ushort tile[64][72];   // row stride 144 B

    const int y = blockIdx.y;
    const float* srcF = nullptr;
    const ushort* srcH = nullptr;
    ushort* dst; int ncols, n0;
    if (y < 16)       { srcF = pre_s;     dst = pre_s_t;   ncols = NIN;  n0 = y * 64; }
    else if (y < 24)  { srcF = post_s;    dst = post_s_t;  ncols = NOUT; n0 = (y - 16) * 64; }
    else if (y < 40)  { srcH = ws_pre16;  dst = pre_tr_t;  ncols = NIN;  n0 = (y - 24) * 64; }
    else              { srcH = ws_post16; dst = post_tr_t; ncols = NOUT; n0 = (y - 40) * 64; }

    const int k0 = blockIdx.x * 64;
    const int r  = threadIdx.x >> 2;     // 0..63 (k-row within tile)
    const int cq = threadIdx.x & 3;      // 0..3  (16-col chunk)

    if (srcF) {
        const float* s = srcF + (size_t)(k0 + r) * ncols + n0 + cq * 16;
        ushort tmp[16];
        #pragma unroll
        for (int v = 0; v < 4; ++v) {
            const float4 f = ((const float4*)s)[v];
            tmp[v * 4 + 0] = f2bf(f.x); tmp[v * 4 + 1] = f2bf(f.y);
            tmp[v * 4 + 2] = f2bf(f.z); tmp[v * 4 + 3] = f2bf(f.w);
        }
        *(ushort8*)&tile[r][cq * 16]     = *(const ushort8*)&tmp[0];
        *(ushort8*)&tile[r][cq * 16 + 8] = *(const ushort8*)&tmp[8];
    } else {
        const ushort* s = srcH + (size_t)(k0 + r) * ncols + n0 + cq * 16;
        *(ushort8*)&tile[r][cq * 16]     = ((const ushort8*)s)[0];
        *(ushort8*)&tile[r][cq * 16 + 8] = ((const ushort8*)s)[1];
    }
    __syncthreads();

    union { ushort u[16]; ushort8 v[2]; } o;
    #pragma unroll
    for (int j = 0; j < 16; ++j) o.u[j] = tile[cq * 16 + j][r];
    ushort* d = dst + (size_t)(n0 + r) * KTOT + k0 + cq * 16;
    ((ushort8*)d)[0] = o.v[0];
    ((ushort8*)d)[1] = o.v[1];
}

// ---------------------------------------------------------------------------
// Kernel 3: dual bf16 MFMA GEMM, 64x64 tile, fused finalize via atomicAdd.
//   P[o,i] = sum_k post_s[k,o]*pre_tr[k,i]
//   D[o,i] = sum_k post_tr[k,o]*pre_s[k,i]
//   out[o,i] += (LR_LTP*(1-w)*P + LR_LTD*w*D)/B    per K-chunk
// grid = (NIN/64=16, NOUT/64=8, KS=5) = 640 blocks; 4 waves 2x2 (32x32 each).
// LDS: 4 operand sections of 4 KB, wave w stages section w.
// ---------------------------------------------------------------------------
__global__ __launch_bounds__(256) void stdp_gemm_dual(
    const ushort* __restrict__ post_s_t, const ushort* __restrict__ post_tr_t,
    const ushort* __restrict__ pre_tr_t, const ushort* __restrict__ pre_s_t,
    const float* __restrict__ wmat, float* __restrict__ out)
{
    __shared__ ushort S[4 * 2048];   // [AsP | AsD | BsP | BsD], 4 KB each

    const int i0 = blockIdx.x * 64;
    const int o0 = blockIdx.y * 64;
    const int k0 = blockIdx.z * KCHUNK;

    const int tid  = threadIdx.x;
    const int w    = tid >> 6;
    const int lane = tid & 63;
    const int quad = lane >> 4;
    const int l16  = lane & 15;
    const int wm   = w & 1;
    const int wn   = w >> 1;

    // wave w stages operand w: 0=post_s(A), 1=post_tr(A), 2=pre_tr(B), 3=pre_s(B)
    const ushort* gbase;
    {
        const ushort* t;
        if (w == 0)      t = post_s_t  + (size_t)o0 * KTOT;
        else if (w == 1) t = post_tr_t + (size_t)o0 * KTOT;
        else if (w == 2) t = pre_tr_t  + (size_t)i0 * KTOT;
        else             t = pre_s_t   + (size_t)i0 * KTOT;
        gbase = t;
    }

    floatx4 accP[2][2], accD[2][2];
    const floatx4 zero4 = {0.f, 0.f, 0.f, 0.f};
    #pragma unroll
    for (int mt = 0; mt < 2; ++mt)
        #pragma unroll
        for (int nt = 0; nt < 2; ++nt) { accP[mt][nt] = zero4; accD[mt][nt] = zero4; }

    for (int kb = k0; kb < k0 + KCHUNK; kb += BK) {
        #pragma unroll
        for (int q = 0; q < 4; ++q) {
            const int chunk = q * 64 + lane;        // 16B chunk 0..255
            const int row   = chunk >> 2;           // 0..63
            const int kob   = (chunk & 3) * 16;
            const char* g = (const char*)gbase + (size_t)row * KROWB + kb * 2 + kob;
            __builtin_amdgcn_global_load_lds(
                (const __attribute__((address_space(1))) void*)g,
                (__attribute__((address_space(3))) void*)((char*)S + w * 4096 + q * 1024),
                16, 0, 0);
        }
        __syncthreads();

        short8 aP[2], aD[2], bP[2], bD[2];
        #pragma unroll
        for (int mt = 0; mt < 2; ++mt) {
            const int r = (wm * 32 + mt * 16 + l16) * 32 + quad * 8;
            aP[mt] = *(const short8*)&S[r];
            aD[mt] = *(const short8*)&S[2048 + r];
        }
        #pragma unroll
        for (int nt = 0; nt < 2; ++nt) {
            const int r = (wn * 32 + nt * 16 + l16) * 32 + quad * 8;
            bP[nt] = *(const short8*)&S[4096 + r];
            bD[nt] = *(const short8*)&S[6144 + r];
        }
        #pragma unroll
        for (int mt = 0; mt < 2; ++mt)
            #pragma unroll
            for (int nt = 0; nt < 2; ++nt) {
                accP[mt][nt] = __builtin_amdgcn_mfma_f32_16x16x32_bf16(
                    aP[mt], bP[nt], accP[mt][nt], 0, 0, 0);
                accD[mt][nt] = __builtin_amdgcn_mfma_f32_16x16x32_bf16(
                    aD[mt], bD[nt], accD[mt][nt], 0, 0, 0);
            }
        __syncthreads();
    }

    // epilogue: C/D layout col = lane&15 (i), row = quad*4+reg (o)
    const float c1 = LR_LTP * INV_B;
    const float c2 = LR_LTD * INV_B;
    #pragma unroll
    for (int mt = 0; mt < 2; ++mt) {
        const int obase = o0 + wm * 32 + mt * 16 + quad * 4;
        #pragma unroll
        for (int nt = 0; nt < 2; ++nt) {
            const int i = i0 + wn * 32 + nt * 16 + l16;
            #pragma unroll
            for (int r = 0; r < 4; ++r) {
                const size_t idx = (size_t)(obase + r) * NIN + i;
                const float wv = wmat[idx];
                const float v = c1 * (1.0f - wv) * accP[mt][nt][r]
                              + c2 * wv          * accD[mt][nt][r];
                atomicAdd(&out[idx], v);
            }
        }
    }
}

extern "C" void kernel_launch(void* const* d_in, const int* in_sizes, int n_in,
                              void* d_out, int out_size, void* d_ws, size_t ws_size,
                              hipStream_t stream) {
    const float* weight   = (const float*)d_in[0];
    const float* pre_s    = (const float*)d_in[1];
    const float* post_s   = (const float*)d_in[2];
    const float* pre_tr0  = (const float*)d_in[3];
    const float* post_tr0 = (const float*)d_in[4];
    float* out = (float*)d_out;

    ushort* u = (ushort*)d_ws;
    ushort* ws_pre16  = u + U_WSPRE;
    ushort* ws_post16 = u + U_WSPOST;
    ushort* pre_s_t   = u + U_PRST;
    ushort* post_s_t  = u + U_POST_ST;
    ushort* pre_tr_t  = u + U_PRTT;
    ushort* post_tr_t = u + U_POTT;

    stdp_traces<<<dim3(BATCH * (NIN + NOUT) / 64), dim3(256), 0, stream>>>(
        pre_s, post_s, pre_tr0, post_tr0, ws_pre16, ws_post16, out);

    stdp_transpose<<<dim3(KTOT / 64, 48), dim3(256), 0, stream>>>(
        pre_s, post_s, ws_pre16, ws_post16, pre_s_t, post_s_t, pre_tr_t, post_tr_t);

    stdp_gemm_dual<<<dim3(NIN / 64, NOUT / 64, KS), dim3(256), 0, stream>>>(
        post_s_t, post_tr_t, pre_tr_t, pre_s_t, weight, out);
}